// Round 1
// baseline (233.115 us; speedup 1.0000x reference)
//
#include <hip/hip_runtime.h>
#include <hip/hip_bf16.h>

typedef unsigned short u16;
typedef __attribute__((ext_vector_type(8))) short short8;
typedef __attribute__((ext_vector_type(4))) float f32x4;

__device__ __forceinline__ u16 f2b(float f) {
  union { float f; unsigned u; } a; a.f = f;
  unsigned r = a.u + 0x7fffu + ((a.u >> 16) & 1u);   // RNE bf16 (finite inputs)
  return (u16)(r >> 16);
}

#define GLD_LDS16(gp, lp) __builtin_amdgcn_global_load_lds( \
    (const __attribute__((address_space(1))) void*)(gp),    \
    (__attribute__((address_space(3))) void*)(lp), 16, 0, 0)

// ---------------- fp32 -> bf16 convert (x, w_qkv, w_proj) ----------------
__global__ __launch_bounds__(256) void cvt3(
    const float* __restrict__ x, const float* __restrict__ wq, const float* __restrict__ wp,
    u16* __restrict__ xb, u16* __restrict__ wqb, u16* __restrict__ wpb)
{
  const int NX = 8192 * 768 / 4, NQ = 2304 * 768 / 4, NP = 768 * 768 / 4;
  int i = blockIdx.x * 256 + threadIdx.x;
  const float* src; u16* dst; int j;
  if (i < NX)            { src = x;  dst = xb;  j = i; }
  else if (i < NX + NQ)  { src = wq; dst = wqb; j = i - NX; }
  else if (i < NX + NQ + NP) { src = wp; dst = wpb; j = i - NX - NQ; }
  else return;
  float4 v = *(const float4*)&src[(size_t)j * 4];
  u16 o[4] = { f2b(v.x), f2b(v.y), f2b(v.z), f2b(v.w) };
  *(uint2*)&dst[(size_t)j * 4] = *(uint2*)o;
}

// ---------------- 128x128 bf16 GEMM, C = A @ Bt^T (both K-contiguous) ----------------
// mode: Cb != nullptr -> bf16 output; else fp32 output + bias
__global__ __launch_bounds__(256) void gemm_bt(
    const u16* __restrict__ A, const u16* __restrict__ Bt,
    u16* __restrict__ Cb, float* __restrict__ Cf, const float* __restrict__ bias,
    int M, int N, int K)
{
  __shared__ u16 Al[128 * 32];
  __shared__ u16 Bl[128 * 32];
  const int tid = threadIdx.x;
  const int lane = tid & 63, wave = tid >> 6;
  const int wr = wave >> 1, wc = wave & 1;
  const int g = lane >> 4, c16 = lane & 15;
  const int m0 = blockIdx.y * 128, n0 = blockIdx.x * 128;

  f32x4 acc[4][4] = {};

  const int c0 = tid, c1 = tid + 256;
  const int r0 = c0 >> 2, o0 = (c0 & 3) * 8;
  const int r1 = c1 >> 2, o1 = (c1 & 3) * 8;
  const u16* a0 = A + (size_t)(m0 + r0) * K + o0;
  const u16* a1 = A + (size_t)(m0 + r1) * K + o1;
  const u16* b0 = Bt + (size_t)(n0 + r0) * K + o0;
  const u16* b1 = Bt + (size_t)(n0 + r1) * K + o1;

  for (int k0 = 0; k0 < K; k0 += 32) {
    GLD_LDS16(a0 + k0, Al + c0 * 8);
    GLD_LDS16(a1 + k0, Al + c1 * 8);
    GLD_LDS16(b0 + k0, Bl + c0 * 8);
    GLD_LDS16(b1 + k0, Bl + c1 * 8);
    __syncthreads();
    short8 af[4], bfr[4];
#pragma unroll
    for (int m = 0; m < 4; ++m)
      af[m] = *(const short8*)&Al[(wr * 64 + m * 16 + c16) * 32 + g * 8];
#pragma unroll
    for (int n = 0; n < 4; ++n)
      bfr[n] = *(const short8*)&Bl[(wc * 64 + n * 16 + c16) * 32 + g * 8];
#pragma unroll
    for (int m = 0; m < 4; ++m)
#pragma unroll
      for (int n = 0; n < 4; ++n)
        acc[m][n] = __builtin_amdgcn_mfma_f32_16x16x32_bf16(af[m], bfr[n], acc[m][n], 0, 0, 0);
    __syncthreads();
  }

  if (Cb) {
#pragma unroll
    for (int m = 0; m < 4; ++m) {
      const int row = m0 + wr * 64 + m * 16 + g * 4;
#pragma unroll
      for (int n = 0; n < 4; ++n) {
        const int col = n0 + wc * 64 + n * 16 + c16;
#pragma unroll
        for (int j = 0; j < 4; ++j)
          Cb[(size_t)(row + j) * N + col] = f2b(acc[m][n][j]);
      }
    }
  } else {
#pragma unroll
    for (int m = 0; m < 4; ++m) {
      const int row = m0 + wr * 64 + m * 16 + g * 4;
#pragma unroll
      for (int n = 0; n < 4; ++n) {
        const int col = n0 + wc * 64 + n * 16 + c16;
        const float bb = bias[col];
#pragma unroll
        for (int j = 0; j < 4; ++j)
          Cf[(size_t)(row + j) * N + col] = acc[m][n][j] + bb;
      }
    }
  }
}

// ---------------- V transpose: vt[bh][d=96][n=1024] from qkv cols 1536.. ----------------
__global__ __launch_bounds__(256) void vtrans(const u16* __restrict__ qkv, u16* __restrict__ vt)
{
  __shared__ u16 Vtl[96 * 72];
  const int tid = threadIdx.x;
  const int bh = blockIdx.x >> 4, nt = blockIdx.x & 15;
  const int b = bh >> 3, h = bh & 7;
  const int n0 = nt * 64;
  const size_t tb = (size_t)b * 1024;
#pragma unroll
  for (int i = 0; i < 3; ++i) {
    int c = tid + i * 256;
    int key = c / 12, cc = c % 12;
    uint4 v = *(const uint4*)&qkv[(tb + n0 + key) * 2304 + 1536 + h * 96 + cc * 8];
    union { uint4 u; u16 s[8]; } cv; cv.u = v;
#pragma unroll
    for (int j = 0; j < 8; ++j)
      Vtl[(cc * 8 + j) * 72 + key] = cv.s[j];
  }
  __syncthreads();
#pragma unroll
  for (int i = 0; i < 3; ++i) {
    int c = tid + i * 256;
    int d = c >> 3, c2 = c & 7;
    *(uint4*)&vt[((size_t)bh * 96 + d) * 1024 + n0 + c2 * 8] = *(const uint4*)&Vtl[d * 72 + c2 * 8];
  }
}

// ---------------- tri-attention ----------------
// grid (8 qtiles, 64 bh), 256 thr = 4 waves x 32 queries. KVBLK=64, 16 tiles.
// No-max softmax: P = exp(S*scale) directly (scores bounded ~|1.1|), l = sum P.
__global__ __launch_bounds__(256, 2) void attn_kernel(
    const u16* __restrict__ qkv, const u16* __restrict__ vt, u16* __restrict__ feat)
{
  __shared__ u16 Kl[3][64 * 40];   // k3,k4,k5 [key][32d], +8 pad
  __shared__ u16 Vl[96 * 72];      // vt tile [d][64keys], +8 pad
  __shared__ u16 Pl[4][32 * 72];   // per-wave P [q][64keys], +8 pad

  const int tid = threadIdx.x;
  const int lane = tid & 63, wave = tid >> 6;
  const int g = lane >> 4, c16 = lane & 15;
  const int qt = blockIdx.x, bh = blockIdx.y;
  const int b = bh >> 3, h = bh & 7;
  const int q0 = qt * 128 + wave * 32;
  const size_t tb = (size_t)b * 1024;

  // Q fragments: qs=0 -> q4 (d 32..63), qs=1 -> q5 (d 64..95); kept in regs all kernel
  short8 qf[2][2];
#pragma unroll
  for (int qs = 0; qs < 2; ++qs)
#pragma unroll
    for (int m = 0; m < 2; ++m)
      qf[qs][m] = *(const short8*)&qkv[(tb + q0 + m * 16 + c16) * 2304 + h * 96 + 32 + 32 * qs + 8 * g];

  f32x4 acc[3][2][2] = {};
  float lsum[3][2][4] = {};

  int kk_key[3], kk_cc[3], vv_d[3], vv_c[3];
#pragma unroll
  for (int i = 0; i < 3; ++i) {
    int c = tid + i * 256;
    kk_key[i] = c / 12; kk_cc[i] = c % 12;
    vv_d[i] = c >> 3;   vv_c[i] = c & 7;
  }
  uint4 kst[3], vst[3];
#pragma unroll
  for (int i = 0; i < 3; ++i) {
    kst[i] = *(const uint4*)&qkv[(tb + kk_key[i]) * 2304 + 768 + h * 96 + kk_cc[i] * 8];
    vst[i] = *(const uint4*)&vt[((size_t)bh * 96 + vv_d[i]) * 1024 + vv_c[i] * 8];
  }

  const float c2s = 0.14724447f;  // scale * log2(e) = 96^-0.5 * 1.4426950
  const int ATT[6] = {0,0,1,1,2,2};
  const int QS[6]  = {0,0,1,1,1,1};
  const int KS[6]  = {0,1,0,2,1,2};

  for (int t = 0; t < 16; ++t) {
    __syncthreads();
#pragma unroll
    for (int i = 0; i < 3; ++i) {
      int part = kk_cc[i] >> 2, g4 = kk_cc[i] & 3;
      *(uint4*)&Kl[part][kk_key[i] * 40 + g4 * 8] = kst[i];
      *(uint4*)&Vl[vv_d[i] * 72 + vv_c[i] * 8] = vst[i];
    }
    if (t < 15) {  // prefetch next tile into regs; HBM latency hides under compute
      int kv0 = (t + 1) * 64;
#pragma unroll
      for (int i = 0; i < 3; ++i) {
        kst[i] = *(const uint4*)&qkv[(tb + kv0 + kk_key[i]) * 2304 + 768 + h * 96 + kk_cc[i] * 8];
        vst[i] = *(const uint4*)&vt[((size_t)bh * 96 + vv_d[i]) * 1024 + kv0 + vv_c[i] * 8];
      }
    }
    __syncthreads();

#pragma unroll
    for (int u = 0; u < 6; ++u) {
      const int att = ATT[u], qs = QS[u], ks = KS[u];
      short8 kf[4];
#pragma unroll
      for (int n = 0; n < 4; ++n)
        kf[n] = *(const short8*)&Kl[ks][(n * 16 + c16) * 40 + g * 8];
      const f32x4 z = {0.f, 0.f, 0.f, 0.f};
      f32x4 S[2][4];
#pragma unroll
      for (int m = 0; m < 2; ++m)
#pragma unroll
        for (int n = 0; n < 4; ++n)
          S[m][n] = __builtin_amdgcn_mfma_f32_16x16x32_bf16(qf[qs][m], kf[n], z, 0, 0, 0);
#pragma unroll
      for (int m = 0; m < 2; ++m)
#pragma unroll
        for (int n = 0; n < 4; ++n)
#pragma unroll
          for (int r = 0; r < 4; ++r) {
            float p = __builtin_amdgcn_exp2f(S[m][n][r] * c2s);
            lsum[att][m][r] += p;
            Pl[wave][(m * 16 + g * 4 + r) * 72 + n * 16 + c16] = f2b(p);
          }
      short8 pa[2][2], vf[2][2];
#pragma unroll
      for (int m = 0; m < 2; ++m)
#pragma unroll
        for (int kk = 0; kk < 2; ++kk)
          pa[m][kk] = *(const short8*)&Pl[wave][(m * 16 + c16) * 72 + kk * 32 + g * 8];
#pragma unroll
      for (int n = 0; n < 2; ++n)
#pragma unroll
        for (int kk = 0; kk < 2; ++kk)
          vf[n][kk] = *(const short8*)&Vl[(ks * 32 + n * 16 + c16) * 72 + kk * 32 + g * 8];
#pragma unroll
      for (int m = 0; m < 2; ++m)
#pragma unroll
        for (int n = 0; n < 2; ++n)
#pragma unroll
          for (int kk = 0; kk < 2; ++kk)
            acc[att][m][n] = __builtin_amdgcn_mfma_f32_16x16x32_bf16(pa[m][kk], vf[n][kk], acc[att][m][n], 0, 0, 0);
    }
  }

  // reduce l across the 16 column-lanes, then normalize + write feat (bf16)
#pragma unroll
  for (int a = 0; a < 3; ++a)
#pragma unroll
    for (int m = 0; m < 2; ++m)
#pragma unroll
      for (int r = 0; r < 4; ++r) {
        float v = lsum[a][m][r];
        v += __shfl_xor(v, 1);
        v += __shfl_xor(v, 2);
        v += __shfl_xor(v, 4);
        v += __shfl_xor(v, 8);
        lsum[a][m][r] = 1.0f / v;
      }
#pragma unroll
  for (int a = 0; a < 3; ++a)
#pragma unroll
    for (int m = 0; m < 2; ++m)
#pragma unroll
      for (int n = 0; n < 2; ++n)
#pragma unroll
        for (int r = 0; r < 4; ++r) {
          int row = q0 + m * 16 + g * 4 + r;
          int col = a * 256 + h * 32 + n * 16 + c16;
          feat[(tb + row) * 768 + col] = f2b(acc[a][m][n][r] * lsum[a][m][r]);
        }
}

// ---------------- launch ----------------
extern "C" void kernel_launch(void* const* d_in, const int* in_sizes, int n_in,
                              void* d_out, int out_size, void* d_ws, size_t ws_size,
                              hipStream_t stream) {
  const float* x  = (const float*)d_in[0];
  const float* wq = (const float*)d_in[1];
  const float* wp = (const float*)d_in[2];
  const float* bp = (const float*)d_in[3];
  float* out = (float*)d_out;

  char* ws = (char*)d_ws;
  u16* xb    = (u16*)(ws);                // 12,582,912 B  (reused as feat after GEMM1)
  u16* wqb   = (u16*)(ws + 12582912);     //  3,538,944 B
  u16* wpb   = (u16*)(ws + 16121856);     //  1,179,648 B
  u16* qkvb  = (u16*)(ws + 17301504);     // 37,748,736 B
  u16* vtb   = (u16*)(ws + 55050240);     // 12,582,912 B  (end: 67,633,152)
  u16* featb = xb;                        // xb is dead after GEMM1

  cvt3<<<8448, 256, 0, stream>>>(x, wq, wp, xb, wqb, wpb);
  gemm_bt<<<dim3(18, 64), 256, 0, stream>>>(xb, wqb, qkvb, nullptr, nullptr, 8192, 2304, 768);
  vtrans<<<1024, 256, 0, stream>>>(qkvb, vtb);
  attn_kernel<<<dim3(8, 64), 256, 0, stream>>>(qkvb, vtb, featb);
  gemm_bt<<<dim3(6, 64), 256, 0, stream>>>(featb, wpb, nullptr, out, bp, 8192, 768, 768);
}

// Round 2
// 191.754 us; speedup vs baseline: 1.2157x; 1.2157x over previous
//
#include <hip/hip_runtime.h>
#include <hip/hip_bf16.h>

typedef unsigned short u16;
typedef __attribute__((ext_vector_type(8))) short short8;
typedef __attribute__((ext_vector_type(4))) float f32x4;

__device__ __forceinline__ u16 f2b(float f) {
  union { float f; unsigned u; } a; a.f = f;
  unsigned r = a.u + 0x7fffu + ((a.u >> 16) & 1u);   // RNE bf16 (finite inputs)
  return (u16)(r >> 16);
}

__device__ __forceinline__ unsigned pkbf16(float lo, float hi) {
  unsigned r;
  asm("v_cvt_pk_bf16_f32 %0, %1, %2" : "=v"(r) : "v"(lo), "v"(hi));
  return r;
}

#define GLD_LDS16(gp, lp) __builtin_amdgcn_global_load_lds( \
    (const __attribute__((address_space(1))) void*)(gp),    \
    (__attribute__((address_space(3))) void*)(lp), 16, 0, 0)

// ---------------- fp32 -> bf16 convert (x, w_qkv, w_proj) ----------------
__global__ __launch_bounds__(256) void cvt3(
    const float* __restrict__ x, const float* __restrict__ wq, const float* __restrict__ wp,
    u16* __restrict__ xb, u16* __restrict__ wqb, u16* __restrict__ wpb)
{
  const int NX = 8192 * 768 / 4, NQ = 2304 * 768 / 4, NP = 768 * 768 / 4;
  int i = blockIdx.x * 256 + threadIdx.x;
  const float* src; u16* dst; int j;
  if (i < NX)            { src = x;  dst = xb;  j = i; }
  else if (i < NX + NQ)  { src = wq; dst = wqb; j = i - NX; }
  else if (i < NX + NQ + NP) { src = wp; dst = wpb; j = i - NX - NQ; }
  else return;
  float4 v = *(const float4*)&src[(size_t)j * 4];
  u16 o[4] = { f2b(v.x), f2b(v.y), f2b(v.z), f2b(v.w) };
  *(uint2*)&dst[(size_t)j * 4] = *(uint2*)o;
}

// ---------------- 128x128 bf16 GEMM, C = A @ Bt^T (both K-contiguous) ----------------
__global__ __launch_bounds__(256) void gemm_bt(
    const u16* __restrict__ A, const u16* __restrict__ Bt,
    u16* __restrict__ Cb, float* __restrict__ Cf, const float* __restrict__ bias,
    int M, int N, int K)
{
  __shared__ u16 Al[128 * 32];
  __shared__ u16 Bl[128 * 32];
  const int tid = threadIdx.x;
  const int lane = tid & 63, wave = tid >> 6;
  const int wr = wave >> 1, wc = wave & 1;
  const int g = lane >> 4, c16 = lane & 15;
  const int m0 = blockIdx.y * 128, n0 = blockIdx.x * 128;

  f32x4 acc[4][4] = {};

  const int c0 = tid, c1 = tid + 256;
  const int r0 = c0 >> 2, o0 = (c0 & 3) * 8;
  const int r1 = c1 >> 2, o1 = (c1 & 3) * 8;
  const u16* a0 = A + (size_t)(m0 + r0) * K + o0;
  const u16* a1 = A + (size_t)(m0 + r1) * K + o1;
  const u16* b0 = Bt + (size_t)(n0 + r0) * K + o0;
  const u16* b1 = Bt + (size_t)(n0 + r1) * K + o1;

  for (int k0 = 0; k0 < K; k0 += 32) {
    GLD_LDS16(a0 + k0, Al + c0 * 8);
    GLD_LDS16(a1 + k0, Al + c1 * 8);
    GLD_LDS16(b0 + k0, Bl + c0 * 8);
    GLD_LDS16(b1 + k0, Bl + c1 * 8);
    __syncthreads();
    short8 af[4], bfr[4];
#pragma unroll
    for (int m = 0; m < 4; ++m)
      af[m] = *(const short8*)&Al[(wr * 64 + m * 16 + c16) * 32 + g * 8];
#pragma unroll
    for (int n = 0; n < 4; ++n)
      bfr[n] = *(const short8*)&Bl[(wc * 64 + n * 16 + c16) * 32 + g * 8];
#pragma unroll
    for (int m = 0; m < 4; ++m)
#pragma unroll
      for (int n = 0; n < 4; ++n)
        acc[m][n] = __builtin_amdgcn_mfma_f32_16x16x32_bf16(af[m], bfr[n], acc[m][n], 0, 0, 0);
    __syncthreads();
  }

  if (Cb) {
#pragma unroll
    for (int m = 0; m < 4; ++m) {
      const int row = m0 + wr * 64 + m * 16 + g * 4;
#pragma unroll
      for (int n = 0; n < 4; ++n) {
        const int col = n0 + wc * 64 + n * 16 + c16;
#pragma unroll
        for (int j = 0; j < 4; ++j)
          Cb[(size_t)(row + j) * N + col] = f2b(acc[m][n][j]);
      }
    }
  } else {
#pragma unroll
    for (int m = 0; m < 4; ++m) {
      const int row = m0 + wr * 64 + m * 16 + g * 4;
#pragma unroll
      for (int n = 0; n < 4; ++n) {
        const int col = n0 + wc * 64 + n * 16 + c16;
        const float bb = bias[col];
#pragma unroll
        for (int j = 0; j < 4; ++j)
          Cf[(size_t)(row + j) * N + col] = acc[m][n][j] + bb;
      }
    }
  }
}

// ---------------- V transpose (key-permuted): vt[bh][d][n], keys reordered ----------------
// Within each 32-key chunk, actual key o is stored at slot kappa = 8*g + 4*np + r
// (o = 16*np + 4*g + r). This makes the PV A-fragment (P, built in-register from
// swapped-QK^T output) and the B-fragment (V) agree on instruction-k ordering.
__global__ __launch_bounds__(256) void vtrans(const u16* __restrict__ qkv, u16* __restrict__ vt)
{
  __shared__ u16 Vtl[96 * 72];
  const int tid = threadIdx.x;
  const int bh = blockIdx.x >> 4, nt = blockIdx.x & 15;
  const int b = bh >> 3, h = bh & 7;
  const int n0 = nt * 64;
  const size_t tb = (size_t)b * 1024;
#pragma unroll
  for (int i = 0; i < 3; ++i) {
    int c = tid + i * 256;
    int key = c / 12, cc = c % 12;
    uint4 v = *(const uint4*)&qkv[(tb + n0 + key) * 2304 + 1536 + h * 96 + cc * 8];
    union { uint4 u; u16 s[8]; } cv; cv.u = v;
#pragma unroll
    for (int j = 0; j < 8; ++j)
      Vtl[(cc * 8 + j) * 72 + key] = cv.s[j];
  }
  __syncthreads();
#pragma unroll
  for (int i = 0; i < 3; ++i) {
    int c = tid + i * 256;
    int d = c >> 3, c2 = c & 7;
    int chunk = c2 >> 2;
    int kA = ((c2 & 1) << 4) | ((c2 & 2) << 1);   // c2&3 = 0,1,2,3 -> 0,16,4,20
    const u16* src = &Vtl[d * 72 + c2 * 8];
    size_t base = ((size_t)bh * 96 + d) * 1024 + n0 + chunk * 32;
    *(uint2*)&vt[base + kA]     = *(const uint2*)(src);
    *(uint2*)&vt[base + kA + 8] = *(const uint2*)(src + 4);
  }
}

// ---------------- tri-attention, swapped-QK^T + in-register P ----------------
// grid (8 qtiles, 64 bh), 256 thr = 4 waves x 32 queries. KVBLK=64, 16 tiles.
// S^T = mfma(K,Q): lane (g,c16) holds S[key=n*16+g*4+r][q=16m+c16] -> P stays
// lane-local for its query; cvt_pk packs PV A-fragments; V is key-permuted.
// u-list deduped: (q5,k5) block feeds both x4 and x5 -> computed once (att=3).
__global__ __launch_bounds__(256, 2) void attn_kernel(
    const u16* __restrict__ qkv, const u16* __restrict__ vt, u16* __restrict__ feat)
{
  __shared__ u16 Kl[3][64 * 40];   // k3,k4,k5 [key][32d], +8 pad
  __shared__ u16 Vl[96 * 72];      // vt tile [d][64 key-slots], +8 pad

  const int tid = threadIdx.x;
  const int lane = tid & 63;
  const int g = lane >> 4, c16 = lane & 15;
  const int qt = blockIdx.x, bh = blockIdx.y;
  const int b = bh >> 3, h = bh & 7;
  const int q0 = qt * 128 + (tid >> 6) * 32;
  const size_t tb = (size_t)b * 1024;

  // Q fragments (B-operand now; same layout as A): qs=0 -> q4, qs=1 -> q5
  short8 qf[2][2];
#pragma unroll
  for (int qs = 0; qs < 2; ++qs)
#pragma unroll
    for (int m = 0; m < 2; ++m)
      qf[qs][m] = *(const short8*)&qkv[(tb + q0 + m * 16 + c16) * 2304 + h * 96 + 32 + 32 * qs + 8 * g];

  f32x4 acc[4][2][2] = {};   // att 0,1,2 + 3 = shared (q5,k5)
  float lsum[4][2] = {};

  int kk_key[3], kk_cc[3], vv_d[3], vv_c[3];
#pragma unroll
  for (int i = 0; i < 3; ++i) {
    int c = tid + i * 256;
    kk_key[i] = c / 12; kk_cc[i] = c % 12;
    vv_d[i] = c >> 3;   vv_c[i] = c & 7;
  }
  uint4 kst[3], vst[3];
#pragma unroll
  for (int i = 0; i < 3; ++i) {
    kst[i] = *(const uint4*)&qkv[(tb + kk_key[i]) * 2304 + 768 + h * 96 + kk_cc[i] * 8];
    vst[i] = *(const uint4*)&vt[((size_t)bh * 96 + vv_d[i]) * 1024 + vv_c[i] * 8];
  }

  const float c2s = 0.14724447f;  // 96^-0.5 * log2(e)
  const int ATT[5] = {0, 0, 1, 3, 2};
  const int QS[5]  = {0, 0, 1, 1, 1};
  const int KS[5]  = {0, 1, 0, 2, 1};

  for (int t = 0; t < 16; ++t) {
    __syncthreads();
#pragma unroll
    for (int i = 0; i < 3; ++i) {
      int part = kk_cc[i] >> 2, g4 = kk_cc[i] & 3;
      *(uint4*)&Kl[part][kk_key[i] * 40 + g4 * 8] = kst[i];
      *(uint4*)&Vl[vv_d[i] * 72 + vv_c[i] * 8] = vst[i];
    }
    if (t < 15) {  // prefetch next tile into regs; HBM latency hides under compute
      int kv0 = (t + 1) * 64;
#pragma unroll
      for (int i = 0; i < 3; ++i) {
        kst[i] = *(const uint4*)&qkv[(tb + kv0 + kk_key[i]) * 2304 + 768 + h * 96 + kk_cc[i] * 8];
        vst[i] = *(const uint4*)&vt[((size_t)bh * 96 + vv_d[i]) * 1024 + kv0 + vv_c[i] * 8];
      }
    }
    __syncthreads();

#pragma unroll
    for (int u = 0; u < 5; ++u) {
      const int att = ATT[u], qs = QS[u], ks = KS[u];
      short8 kf[4], vf[2][2];
#pragma unroll
      for (int n = 0; n < 4; ++n)
        kf[n] = *(const short8*)&Kl[ks][(n * 16 + c16) * 40 + g * 8];
#pragma unroll
      for (int n = 0; n < 2; ++n)
#pragma unroll
        for (int kk = 0; kk < 2; ++kk)
          vf[n][kk] = *(const short8*)&Vl[(ks * 32 + n * 16 + c16) * 72 + kk * 32 + g * 8];

      const f32x4 z = {0.f, 0.f, 0.f, 0.f};
#pragma unroll
      for (int m = 0; m < 2; ++m) {
        f32x4 St[4];
#pragma unroll
        for (int n = 0; n < 4; ++n)
          St[n] = __builtin_amdgcn_mfma_f32_16x16x32_bf16(kf[n], qf[qs][m], z, 0, 0, 0);
        float p[4][4];
#pragma unroll
        for (int n = 0; n < 4; ++n)
#pragma unroll
          for (int r = 0; r < 4; ++r) {
            p[n][r] = __builtin_amdgcn_exp2f(St[n][r] * c2s);
            lsum[att][m] += p[n][r];
          }
        short8 pa[2];
#pragma unroll
        for (int kk = 0; kk < 2; ++kk) {
          union { unsigned u[4]; short8 s; } w;
          w.u[0] = pkbf16(p[2 * kk][0],     p[2 * kk][1]);
          w.u[1] = pkbf16(p[2 * kk][2],     p[2 * kk][3]);
          w.u[2] = pkbf16(p[2 * kk + 1][0], p[2 * kk + 1][1]);
          w.u[3] = pkbf16(p[2 * kk + 1][2], p[2 * kk + 1][3]);
          pa[kk] = w.s;
        }
#pragma unroll
        for (int n = 0; n < 2; ++n)
#pragma unroll
          for (int kk = 0; kk < 2; ++kk)
            acc[att][m][n] = __builtin_amdgcn_mfma_f32_16x16x32_bf16(pa[kk], vf[n][kk], acc[att][m][n], 0, 0, 0);
      }
    }
  }

  // fold shared (q5,k5) block into x4 (att1) and x5 (att2)
#pragma unroll
  for (int m = 0; m < 2; ++m) {
    lsum[1][m] += lsum[3][m];
    lsum[2][m] += lsum[3][m];
#pragma unroll
    for (int n = 0; n < 2; ++n) {
      acc[1][m][n] += acc[3][m][n];
      acc[2][m][n] += acc[3][m][n];
    }
  }

  // denominator: reduce over g-groups (lanes ^16, ^32), then redistribute to
  // the acc layout (lane (g,c16) rows are q = 16m + 4g + r; denom lives at c16' = 4g+r)
  const int srcb = (lane & 48) | ((lane >> 2) & 12);
  float inv[3][2][4];
#pragma unroll
  for (int a = 0; a < 3; ++a)
#pragma unroll
    for (int m = 0; m < 2; ++m) {
      float v = lsum[a][m];
      v += __shfl_xor(v, 16);
      v += __shfl_xor(v, 32);
#pragma unroll
      for (int r = 0; r < 4; ++r)
        inv[a][m][r] = 1.0f / __shfl(v, srcb | r);
    }

#pragma unroll
  for (int a = 0; a < 3; ++a)
#pragma unroll
    for (int m = 0; m < 2; ++m)
#pragma unroll
      for (int n = 0; n < 2; ++n)
#pragma unroll
        for (int r = 0; r < 4; ++r) {
          int row = q0 + m * 16 + g * 4 + r;
          int col = a * 256 + h * 32 + n * 16 + c16;
          feat[(tb + row) * 768 + col] = f2b(acc[a][m][n][r] * inv[a][m][r]);
        }
}

// ---------------- launch ----------------
extern "C" void kernel_launch(void* const* d_in, const int* in_sizes, int n_in,
                              void* d_out, int out_size, void* d_ws, size_t ws_size,
                              hipStream_t stream) {
  const float* x  = (const float*)d_in[0];
  const float* wq = (const float*)d_in[1];
  const float* wp = (const float*)d_in[2];
  const float* bp = (const float*)d_in[3];
  float* out = (float*)d_out;

  char* ws = (char*)d_ws;
  u16* xb    = (u16*)(ws);                // 12,582,912 B  (reused as feat after GEMM1)
  u16* wqb   = (u16*)(ws + 12582912);     //  3,538,944 B
  u16* wpb   = (u16*)(ws + 16121856);     //  1,179,648 B
  u16* qkvb  = (u16*)(ws + 17301504);     // 37,748,736 B
  u16* vtb   = (u16*)(ws + 55050240);     // 12,582,912 B  (end: 67,633,152)
  u16* featb = xb;                        // xb is dead after GEMM1

  cvt3<<<8448, 256, 0, stream>>>(x, wq, wp, xb, wqb, wpb);
  gemm_bt<<<dim3(18, 64), 256, 0, stream>>>(xb, wqb, qkvb, nullptr, nullptr, 8192, 2304, 768);
  vtrans<<<1024, 256, 0, stream>>>(qkvb, vtb);
  attn_kernel<<<dim3(8, 64), 256, 0, stream>>>(qkvb, vtb, featb);
  gemm_bt<<<dim3(6, 64), 256, 0, stream>>>(featb, wpb, nullptr, out, bp, 8192, 768, 768);
}